// Round 3
// baseline (278.633 us; speedup 1.0000x reference)
//
#include <hip/hip_runtime.h>
#include <stdint.h>

// MHA: B=2, S=2048, DIM=1024, H=16, HD=64, causal. fp32 I/O, bf16 MFMA internal.
// Pipeline: wconvert (weights->bf16) -> proj3 (Xq, Xk, Xvt[dim][token]) ->
//           flash (transposed-S, double-buffered ald16 staging) -> outproj.

typedef short s16x8 __attribute__((ext_vector_type(8)));
typedef float f32x4 __attribute__((ext_vector_type(4)));

#define MFMA_BF16 __builtin_amdgcn_mfma_f32_16x16x32_bf16

static __device__ __forceinline__ unsigned short f2bf(float f) {
    union { float f; unsigned u; } x{f};
    unsigned r = x.u + 0x7fff + ((x.u >> 16) & 1);   // RNE
    return (unsigned short)(r >> 16);
}
static __device__ __forceinline__ unsigned pk2(float a, float b) {
    return (unsigned)f2bf(a) | ((unsigned)f2bf(b) << 16);
}

// async 16B global->LDS: dest is wave-uniform base, lane i lands at base + i*16B.
static __device__ __forceinline__ void ald16(unsigned short* lds, const unsigned short* g) {
    __builtin_amdgcn_global_load_lds(
        (const __attribute__((address_space(1))) unsigned int*)g,
        (__attribute__((address_space(3))) unsigned int*)lds, 16, 0, 0);
}

// ---------------------------------------------------------------------------
// wconvert: wq,wk,wv,wo fp32 [1M each] -> contiguous bf16 Wb[4M]
// ---------------------------------------------------------------------------
__global__ __launch_bounds__(256) void wconvert_kernel(
        const float* __restrict__ wq, const float* __restrict__ wk,
        const float* __restrict__ wv, const float* __restrict__ wo,
        unsigned short* __restrict__ Wb) {
    const size_t idx = ((size_t)blockIdx.x * 256 + threadIdx.x) * 8;
    const int region = (int)(idx >> 20);
    const size_t off = idx & 1048575;
    const float* src = region == 0 ? wq : region == 1 ? wk : region == 2 ? wv : wo;
    const float4* p = (const float4*)(src + off);
    float4 a = p[0], b = p[1];
    uint4 u;
    u.x = pk2(a.x, a.y); u.y = pk2(a.z, a.w);
    u.z = pk2(b.x, b.y); u.w = pk2(b.z, b.w);
    *(uint4*)(Wb + idx) = u;
}

// ---------------------------------------------------------------------------
// proj3: C[4096x1024] = A_fp32 @ W_bf16^T. 128x128 tile, BK=32. grid (8,32,3).
// A: VGPR fp32->bf16 staging, padded LDS (bank-clean). B: ald16 with
// source-permuted swizzle (key (r>>1)&3) so fragment reads are 2-way (free).
// ---------------------------------------------------------------------------
__global__ __launch_bounds__(256) void proj3_kernel(
        const float* __restrict__ q, const float* __restrict__ k, const float* __restrict__ v,
        const unsigned short* __restrict__ Wb,
        unsigned short* __restrict__ Xq, unsigned short* __restrict__ Xk,
        unsigned short* __restrict__ Xvt) {
    constexpr int Kd = 1024;
    __shared__ unsigned short lsA[128 * 40];   // padded rows (80B): conflict-free
    __shared__ unsigned short lsB[128 * 32];   // swizzled image via source permute

    const int z = blockIdx.z;
    const float* A = z == 0 ? q : z == 1 ? k : v;
    const unsigned short* Bw = Wb + (size_t)z * 1048576;

    const int t = threadIdx.x;
    const int m0 = blockIdx.y * 128, n0 = blockIdx.x * 128;
    const int w = t >> 6, lane = t & 63, fr = lane & 15, g = lane >> 4, fq = g * 8;
    const int wm = (w >> 1) * 64, wn = (w & 1) * 64;
    const int ar = t >> 1, ac = (t & 1) * 16;            // A staging
    const int brow = t >> 2;                             // B staging row 0..63
    const int cB = (t & 3) ^ ((t >> 3) & 3);             // permuted source chunk
    const int sB = g ^ ((fr >> 1) & 3);                  // frag-read slot

    f32x4 acc[4][4] = {};

    for (int k0 = 0; k0 < Kd; k0 += 32) {
        // async B (swizzled image): 2 ald16/thread-wave covering 128 rows
        ald16(lsB + (size_t)w * 512,        Bw + (size_t)(n0 + brow) * Kd + k0 + cB * 8);
        ald16(lsB + 2048 + (size_t)w * 512, Bw + (size_t)(n0 + 64 + brow) * Kd + k0 + cB * 8);
        // A: fp32 -> bf16 via VGPR
        {
            const float4* pa = (const float4*)(A + (size_t)(m0 + ar) * Kd + k0 + ac);
            float4 a0 = pa[0], a1 = pa[1], a2 = pa[2], a3 = pa[3];
            uint4 u0, u1;
            u0.x = pk2(a0.x, a0.y); u0.y = pk2(a0.z, a0.w);
            u0.z = pk2(a1.x, a1.y); u0.w = pk2(a1.z, a1.w);
            u1.x = pk2(a2.x, a2.y); u1.y = pk2(a2.z, a2.w);
            u1.z = pk2(a3.x, a3.y); u1.w = pk2(a3.z, a3.w);
            *(uint4*)(lsA + ar * 40 + ac)     = u0;
            *(uint4*)(lsA + ar * 40 + ac + 8) = u1;
        }
        __syncthreads();

        s16x8 af[4], bfv[4];
#pragma unroll
        for (int mi = 0; mi < 4; ++mi)
            af[mi] = *(const s16x8*)(lsA + (wm + mi * 16 + fr) * 40 + fq);
#pragma unroll
        for (int ni = 0; ni < 4; ++ni)
            bfv[ni] = *(const s16x8*)(lsB + (wn + ni * 16 + fr) * 32 + sB * 8);
#pragma unroll
        for (int mi = 0; mi < 4; ++mi)
#pragma unroll
            for (int ni = 0; ni < 4; ++ni)
                acc[mi][ni] = MFMA_BF16(af[mi], bfv[ni], acc[mi][ni], 0, 0, 0);
        __syncthreads();
    }

    if (z != 2) {
        unsigned short* C = z ? Xk : Xq;
#pragma unroll
        for (int mi = 0; mi < 4; ++mi)
#pragma unroll
            for (int ni = 0; ni < 4; ++ni)
#pragma unroll
                for (int reg = 0; reg < 4; ++reg)
                    C[(size_t)(m0 + wm + mi * 16 + g * 4 + reg) * 1024 +
                      n0 + wn + ni * 16 + fr] = f2bf(acc[mi][ni][reg]);
    } else {
        // Xvt[dim][token]: pack 4 consecutive tokens (regs) per 8B store
#pragma unroll
        for (int mi = 0; mi < 4; ++mi)
#pragma unroll
            for (int ni = 0; ni < 4; ++ni) {
                uint2 u;
                u.x = pk2(acc[mi][ni][0], acc[mi][ni][1]);
                u.y = pk2(acc[mi][ni][2], acc[mi][ni][3]);
                *(uint2*)(Xvt + (size_t)(n0 + wn + ni * 16 + fr) * 4096 +
                          m0 + wm + mi * 16 + g * 4) = u;
            }
    }
}

// ---------------------------------------------------------------------------
// flash attention, transposed-S, double-buffered ald16 staging.
// grid (32 qtiles desc, 32 b*h), 256 thr. Wave owns 16 q (q = lane&15).
// LDS image: 64x64 bf16, chunk slot s holds source chunk s^(r&7) (bank-clean).
// ---------------------------------------------------------------------------
static __device__ __forceinline__ void stage_tiles(
        const unsigned short* __restrict__ Xk, const unsigned short* __restrict__ Xvt,
        unsigned short* Kd, unsigned short* Vd,
        size_t rbase, int cbase, int kt, int w, int lane) {
    const int r0 = w * 16 + (lane >> 3);       // tile row, pass 0
    const int r1 = r0 + 8;                     // pass 1
    const int s  = lane & 7;
    const int c0 = s ^ (r0 & 7);               // permuted source chunk
    const int c1 = s ^ (r1 & 7);
    const unsigned short* ks = Xk + (rbase + kt * 64) * 1024 + cbase;
    ald16(Kd + (w * 16) * 64,     ks + (size_t)r0 * 1024 + c0 * 8);
    ald16(Kd + (w * 16 + 8) * 64, ks + (size_t)r1 * 1024 + c1 * 8);
    const unsigned short* vs = Xvt + rbase + kt * 64;
    ald16(Vd + (w * 16) * 64,     vs + (size_t)(cbase + r0) * 4096 + c0 * 8);
    ald16(Vd + (w * 16 + 8) * 64, vs + (size_t)(cbase + r1) * 4096 + c1 * 8);
}

__global__ __launch_bounds__(256) void flash_attn_kernel(
        const unsigned short* __restrict__ Xq, const unsigned short* __restrict__ Xk,
        const unsigned short* __restrict__ Xvt, unsigned short* __restrict__ Oa) {
    __shared__ unsigned short Kls[2][64 * 64];
    __shared__ unsigned short Vls[2][64 * 64];
    __shared__ unsigned short Pls[4 * 16 * 64];

    const int t = threadIdx.x;
    const int qt = 31 - (int)blockIdx.x;       // descending work (LPT)
    const int bh = blockIdx.y;
    const int b = bh >> 4, h = bh & 15;
    const size_t rbase = (size_t)b * 2048;
    const int cbase = h * 64;

    const int w = t >> 6, lane = t & 63, fr = lane & 15, g = lane >> 4, fq = g * 8;
    const int qrow = qt * 64 + w * 16 + fr;
    unsigned short* Pw = Pls + w * 1024;

    const unsigned short* qp = Xq + (rbase + qrow) * 1024 + cbase;
    s16x8 qf0 = *(const s16x8*)(qp + fq);
    s16x8 qf1 = *(const s16x8*)(qp + 32 + fq);

    const float SCL = 0.125f * 1.44269504089f; // 1/sqrt(64)*log2(e); exp2 softmax
    float m_i = -1e30f, l_i = 0.f;
    f32x4 oacc[4] = {};

    stage_tiles(Xk, Xvt, Kls[0], Vls[0], rbase, cbase, 0, w, lane);
    __syncthreads();   // drains prologue ald16

    for (int kt = 0; kt <= qt; ++kt) {
        const int cur = kt & 1;
        if (kt < qt)   // prefetch next tiles into alternate buffer (hidden by compute)
            stage_tiles(Xk, Xvt, Kls[cur ^ 1], Vls[cur ^ 1], rbase, cbase, kt + 1, w, lane);

        // ---- S^T = K(A) x Q(B): rows = keys, cols = q ----
        float p[4][4];
        float mloc = -1e30f;
#pragma unroll
        for (int m16 = 0; m16 < 4; ++m16) {
            const int krow = m16 * 16 + fr;
            s16x8 kf0 = *(const s16x8*)(&Kls[cur][krow * 64 + ((g ^ (fr & 7)) * 8)]);
            s16x8 kf1 = *(const s16x8*)(&Kls[cur][krow * 64 + (((4 + g) ^ (fr & 7)) * 8)]);
            f32x4 sf = {};
            sf = MFMA_BF16(kf0, qf0, sf, 0, 0, 0);
            sf = MFMA_BF16(kf1, qf1, sf, 0, 0, 0);
            if (kt == qt) {
#pragma unroll
                for (int r = 0; r < 4; ++r) {
                    const int keyg = kt * 64 + m16 * 16 + g * 4 + r;
                    const float x = sf[r] * SCL;
                    p[m16][r] = (keyg <= qrow) ? x : -1e30f;
                }
            } else {
#pragma unroll
                for (int r = 0; r < 4; ++r) p[m16][r] = sf[r] * SCL;
            }
#pragma unroll
            for (int r = 0; r < 4; ++r) mloc = fmaxf(mloc, p[m16][r]);
        }
        mloc = fmaxf(mloc, __shfl_xor(mloc, 16, 64));
        mloc = fmaxf(mloc, __shfl_xor(mloc, 32, 64));

        const float mn = fmaxf(m_i, mloc);
        const float alpha = exp2f(m_i - mn);
        m_i = mn;
        float s_loc = 0.f;
#pragma unroll
        for (int m16 = 0; m16 < 4; ++m16)
#pragma unroll
            for (int r = 0; r < 4; ++r) {
                const float e = exp2f(p[m16][r] - mn);
                p[m16][r] = e;
                s_loc += e;
            }
        s_loc += __shfl_xor(s_loc, 16, 64);
        s_loc += __shfl_xor(s_loc, 32, 64);
        l_i = l_i * alpha + s_loc;
#pragma unroll
        for (int n = 0; n < 4; ++n)
#pragma unroll
            for (int r = 0; r < 4; ++r) oacc[n][r] *= alpha;

        // ---- P: C-layout -> B-operand via per-wave LDS (in-wave lgkm only) ----
#pragma unroll
        for (int m16 = 0; m16 < 4; ++m16) {
            uint2 u;
            u.x = pk2(p[m16][0], p[m16][1]);
            u.y = pk2(p[m16][2], p[m16][3]);
            const int ch = 2 * m16 + (g >> 1);
            *(uint2*)(Pw + fr * 64 + ((ch ^ (fr & 7)) * 8) + (g & 1) * 4) = u;
        }
        __asm__ __volatile__("" ::: "memory");
        s16x8 pf0 = *(const s16x8*)(Pw + fr * 64 + ((g ^ (fr & 7)) * 8));
        s16x8 pf1 = *(const s16x8*)(Pw + fr * 64 + (((4 + g) ^ (fr & 7)) * 8));

        // ---- O^T += Vt(A) x P(B) ----
#pragma unroll
        for (int m16 = 0; m16 < 4; ++m16) {
            const int vrow = m16 * 16 + fr;
            s16x8 vf0 = *(const s16x8*)(&Vls[cur][vrow * 64 + ((g ^ (fr & 7)) * 8)]);
            s16x8 vf1 = *(const s16x8*)(&Vls[cur][vrow * 64 + (((4 + g) ^ (fr & 7)) * 8)]);
            oacc[m16] = MFMA_BF16(vf0, pf0, oacc[m16], 0, 0, 0);
            oacc[m16] = MFMA_BF16(vf1, pf1, oacc[m16], 0, 0, 0);
        }
        __syncthreads();   // one barrier/iter: protects buffer swap + drains prefetch
    }

    const float inv = 1.0f / l_i;
#pragma unroll
    for (int m16 = 0; m16 < 4; ++m16) {
        uint2 u;
        u.x = pk2(oacc[m16][0] * inv, oacc[m16][1] * inv);
        u.y = pk2(oacc[m16][2] * inv, oacc[m16][3] * inv);
        *(uint2*)(Oa + (rbase + qrow) * 1024 + cbase + m16 * 16 + g * 4) = u;
    }
}

// ---------------------------------------------------------------------------
// outproj: out_fp32[4096x1024] = Oa_bf16 @ Wo_bf16^T. 64x128 tile, BK=32,
// full ald16 staging with source-permuted swizzle. grid (8, 64).
// ---------------------------------------------------------------------------
__global__ __launch_bounds__(256) void outproj_kernel(
        const unsigned short* __restrict__ Oa, const unsigned short* __restrict__ Wo,
        float* __restrict__ out) {
    constexpr int Kd = 1024;
    __shared__ unsigned short lsA[64 * 32];
    __shared__ unsigned short lsB[128 * 32];

    const int t = threadIdx.x;
    const int m0 = blockIdx.y * 64, n0 = blockIdx.x * 128;
    const int w = t >> 6, lane = t & 63, fr = lane & 15, g = lane >> 4;
    const int wm = (w >> 1) * 32, wn = (w & 1) * 64;
    const int brow = t >> 2;
    const int cB = (t & 3) ^ ((t >> 3) & 3);
    const int sB = g ^ ((fr >> 1) & 3);

    f32x4 acc[2][4] = {};

    for (int k0 = 0; k0 < Kd; k0 += 32) {
        ald16(lsA + (size_t)w * 512,        Oa + (size_t)(m0 + brow) * Kd + k0 + cB * 8);
        ald16(lsB + (size_t)w * 512,        Wo + (size_t)(n0 + brow) * Kd + k0 + cB * 8);
        ald16(lsB + 2048 + (size_t)w * 512, Wo + (size_t)(n0 + 64 + brow) * Kd + k0 + cB * 8);
        __syncthreads();

        s16x8 af[2], bfv[4];
#pragma unroll
        for (int mi = 0; mi < 2; ++mi)
            af[mi] = *(const s16x8*)(lsA + (wm + mi * 16 + fr) * 32 + sB * 8);
#pragma unroll
        for (int ni = 0; ni < 4; ++ni)
            bfv[ni] = *(const s16x8*)(lsB + (wn + ni * 16 + fr) * 32 + sB * 8);
#pragma unroll
        for (int mi = 0; mi < 2; ++mi)
#pragma unroll
            for (int ni = 0; ni < 4; ++ni)
                acc[mi][ni] = MFMA_BF16(af[mi], bfv[ni], acc[mi][ni], 0, 0, 0);
        __syncthreads();
    }

#pragma unroll
    for (int mi = 0; mi < 2; ++mi)
#pragma unroll
        for (int ni = 0; ni < 4; ++ni)
#pragma unroll
            for (int reg = 0; reg < 4; ++reg)
                out[(size_t)(m0 + wm + mi * 16 + g * 4 + reg) * 1024 +
                    n0 + wn + ni * 16 + fr] = acc[mi][ni][reg];
}

// ---------------------------------------------------------------------------
extern "C" void kernel_launch(void* const* d_in, const int* in_sizes, int n_in,
                              void* d_out, int out_size, void* d_ws, size_t ws_size,
                              hipStream_t stream) {
    const float* q  = (const float*)d_in[0];
    const float* k  = (const float*)d_in[1];
    const float* v  = (const float*)d_in[2];
    const float* wq = (const float*)d_in[3];
    const float* wk = (const float*)d_in[4];
    const float* wv = (const float*)d_in[5];
    const float* wo = (const float*)d_in[6];
    float* out = (float*)d_out;

    // workspace: Wb 8MB | Xq 8MB | Xk 8MB | Xvt 8MB | Oa 8MB  (40MB total)
    unsigned short* Wb  = (unsigned short*)d_ws;
    unsigned short* Xq  = Wb  + 4 * 1048576;
    unsigned short* Xk  = Xq  + 4194304;
    unsigned short* Xvt = Xk  + 4194304;
    unsigned short* Oa  = Xvt + 4194304;

    wconvert_kernel<<<2048, 256, 0, stream>>>(wq, wk, wv, wo, Wb);
    proj3_kernel<<<dim3(8, 32, 3), 256, 0, stream>>>(q, k, v, Wb, Xq, Xk, Xvt);
    flash_attn_kernel<<<dim3(32, 32), 256, 0, stream>>>(Xq, Xk, Xvt, Oa);
    outproj_kernel<<<dim3(8, 64), 256, 0, stream>>>(Oa, Wb + 3 * 1048576, out);
}

// Round 4
// 244.533 us; speedup vs baseline: 1.1395x; 1.1395x over previous
//
#include <hip/hip_runtime.h>
#include <stdint.h>

// MHA: B=2, S=2048, DIM=1024, H=16, HD=64, causal. fp32 I/O, bf16 MFMA internal.
// Pipeline: wconvert (weights->bf16) -> proj3 (Xq, Xk, Xvt[dim][token]) ->
//           flash (transposed-S, statically balanced q-tile pairs) -> outproj.

typedef short s16x8 __attribute__((ext_vector_type(8)));
typedef float f32x4 __attribute__((ext_vector_type(4)));

#define MFMA_BF16 __builtin_amdgcn_mfma_f32_16x16x32_bf16

static __device__ __forceinline__ unsigned short f2bf(float f) {
    union { float f; unsigned u; } x{f};
    unsigned r = x.u + 0x7fff + ((x.u >> 16) & 1);   // RNE
    return (unsigned short)(r >> 16);
}
static __device__ __forceinline__ unsigned pk2(float a, float b) {
    return (unsigned)f2bf(a) | ((unsigned)f2bf(b) << 16);
}

// async 16B global->LDS: dest is wave-uniform base, lane i lands at base + i*16B.
static __device__ __forceinline__ void ald16(unsigned short* lds, const unsigned short* g) {
    __builtin_amdgcn_global_load_lds(
        (const __attribute__((address_space(1))) unsigned int*)g,
        (__attribute__((address_space(3))) unsigned int*)lds, 16, 0, 0);
}

// ---------------------------------------------------------------------------
// wconvert: wq,wk,wv,wo fp32 [1M each] -> contiguous bf16 Wb[4M]
// ---------------------------------------------------------------------------
__global__ __launch_bounds__(256) void wconvert_kernel(
        const float* __restrict__ wq, const float* __restrict__ wk,
        const float* __restrict__ wv, const float* __restrict__ wo,
        unsigned short* __restrict__ Wb) {
    const size_t idx = ((size_t)blockIdx.x * 256 + threadIdx.x) * 8;
    const int region = (int)(idx >> 20);
    const size_t off = idx & 1048575;
    const float* src = region == 0 ? wq : region == 1 ? wk : region == 2 ? wv : wo;
    const float4* p = (const float4*)(src + off);
    float4 a = p[0], b = p[1];
    uint4 u;
    u.x = pk2(a.x, a.y); u.y = pk2(a.z, a.w);
    u.z = pk2(b.x, b.y); u.w = pk2(b.z, b.w);
    *(uint4*)(Wb + idx) = u;
}

// ---------------------------------------------------------------------------
// proj3: C[4096x1024] = A_fp32 @ W_bf16^T. 128x128 tile, BK=32. grid (8,32,3).
// A: VGPR fp32->bf16 staging, padded LDS. B: ald16, source-permuted swizzle.
// z==2: transpose epilogue through per-wave LDS -> coalesced Xvt[dim][token].
// ---------------------------------------------------------------------------
__global__ __launch_bounds__(256) void proj3_kernel(
        const float* __restrict__ q, const float* __restrict__ k, const float* __restrict__ v,
        const unsigned short* __restrict__ Wb,
        unsigned short* __restrict__ Xq, unsigned short* __restrict__ Xk,
        unsigned short* __restrict__ Xvt) {
    constexpr int Kd = 1024;
    __shared__ unsigned short lsA[128 * 40];   // padded rows (80B): conflict-free
    __shared__ unsigned short lsB[128 * 32];   // swizzled image via source permute
    __shared__ unsigned short Tls[4 * 64 * 68]; // per-wave transpose tile (z==2)

    const int z = blockIdx.z;
    const float* A = z == 0 ? q : z == 1 ? k : v;
    const unsigned short* Bw = Wb + (size_t)z * 1048576;

    const int t = threadIdx.x;
    const int m0 = blockIdx.y * 128, n0 = blockIdx.x * 128;
    const int w = t >> 6, lane = t & 63, fr = lane & 15, g = lane >> 4, fq = g * 8;
    const int wm = (w >> 1) * 64, wn = (w & 1) * 64;
    const int ar = t >> 1, ac = (t & 1) * 16;            // A staging
    const int brow = t >> 2;                             // B staging row
    const int cB = (t & 3) ^ ((t >> 3) & 3);             // permuted source chunk
    const int sB = g ^ ((fr >> 1) & 3);                  // frag-read slot

    f32x4 acc[4][4] = {};

    for (int k0 = 0; k0 < Kd; k0 += 32) {
        ald16(lsB + (size_t)w * 512,        Bw + (size_t)(n0 + brow) * Kd + k0 + cB * 8);
        ald16(lsB + 2048 + (size_t)w * 512, Bw + (size_t)(n0 + 64 + brow) * Kd + k0 + cB * 8);
        {
            const float4* pa = (const float4*)(A + (size_t)(m0 + ar) * Kd + k0 + ac);
            float4 a0 = pa[0], a1 = pa[1], a2 = pa[2], a3 = pa[3];
            uint4 u0, u1;
            u0.x = pk2(a0.x, a0.y); u0.y = pk2(a0.z, a0.w);
            u0.z = pk2(a1.x, a1.y); u0.w = pk2(a1.z, a1.w);
            u1.x = pk2(a2.x, a2.y); u1.y = pk2(a2.z, a2.w);
            u1.z = pk2(a3.x, a3.y); u1.w = pk2(a3.z, a3.w);
            *(uint4*)(lsA + ar * 40 + ac)     = u0;
            *(uint4*)(lsA + ar * 40 + ac + 8) = u1;
        }
        __syncthreads();

        s16x8 af[4], bfv[4];
#pragma unroll
        for (int mi = 0; mi < 4; ++mi)
            af[mi] = *(const s16x8*)(lsA + (wm + mi * 16 + fr) * 40 + fq);
#pragma unroll
        for (int ni = 0; ni < 4; ++ni)
            bfv[ni] = *(const s16x8*)(lsB + (wn + ni * 16 + fr) * 32 + sB * 8);
#pragma unroll
        for (int mi = 0; mi < 4; ++mi)
#pragma unroll
            for (int ni = 0; ni < 4; ++ni)
                acc[mi][ni] = MFMA_BF16(af[mi], bfv[ni], acc[mi][ni], 0, 0, 0);
        __syncthreads();
    }

    if (z != 2) {
        unsigned short* C = z ? Xk : Xq;
#pragma unroll
        for (int mi = 0; mi < 4; ++mi)
#pragma unroll
            for (int ni = 0; ni < 4; ++ni)
#pragma unroll
                for (int reg = 0; reg < 4; ++reg)
                    C[(size_t)(m0 + wm + mi * 16 + g * 4 + reg) * 1024 +
                      n0 + wn + ni * 16 + fr] = f2bf(acc[mi][ni][reg]);
    } else {
        // per-wave 64x64 transpose via LDS, then coalesced b128 stores
        unsigned short* T = Tls + w * (64 * 68);
#pragma unroll
        for (int mi = 0; mi < 4; ++mi)
#pragma unroll
            for (int ni = 0; ni < 4; ++ni) {
                uint2 u;
                u.x = pk2(acc[mi][ni][0], acc[mi][ni][1]);
                u.y = pk2(acc[mi][ni][2], acc[mi][ni][3]);
                *(uint2*)(T + (ni * 16 + fr) * 68 + mi * 16 + g * 4) = u;
            }
        __asm__ __volatile__("" ::: "memory");   // in-wave LDS write->read order
#pragma unroll
        for (int pass = 0; pass < 8; ++pass) {
            const int row = pass * 8 + (lane >> 3);   // n' 0..63 (dim within quadrant)
            const int chk = lane & 7;                 // m' chunk (tokens)
            uint4 d = *(const uint4*)(T + row * 68 + chk * 8);
            *(uint4*)(Xvt + (size_t)(n0 + wn + row) * 4096 + m0 + wm + chk * 8) = d;
        }
    }
}

// ---------------------------------------------------------------------------
// flash attention, transposed-S, statically balanced q-tile pairs.
// grid (16, 32): block j handles q-tiles H=31-j and L=j (33 units, constant).
// Both slabs share one K/V staging per kt; interleaved chains give in-wave ILP.
// ---------------------------------------------------------------------------
static __device__ __forceinline__ void slab_tail(
        const f32x4 sf[4], int kt, int qt, int qrow,
        float& m_i, float& l_i, f32x4* oacc, unsigned short* Pw,
        const s16x8 vf[4][2], int fr, int g, float SCL) {
    float p[4][4];
    float mloc = -1e30f;
    const bool diag = (kt == qt);
#pragma unroll
    for (int m16 = 0; m16 < 4; ++m16)
#pragma unroll
        for (int r = 0; r < 4; ++r) {
            const int keyg = kt * 64 + m16 * 16 + g * 4 + r;
            float x = sf[m16][r] * SCL;
            if (diag) x = (keyg <= qrow) ? x : -1e30f;
            p[m16][r] = x;
            mloc = fmaxf(mloc, x);
        }
    mloc = fmaxf(mloc, __shfl_xor(mloc, 16, 64));
    mloc = fmaxf(mloc, __shfl_xor(mloc, 32, 64));
    const float mn = fmaxf(m_i, mloc);
    const float alpha = exp2f(m_i - mn);
    m_i = mn;
    float s_loc = 0.f;
#pragma unroll
    for (int m16 = 0; m16 < 4; ++m16)
#pragma unroll
        for (int r = 0; r < 4; ++r) {
            const float e = exp2f(p[m16][r] - mn);
            p[m16][r] = e;
            s_loc += e;
        }
    s_loc += __shfl_xor(s_loc, 16, 64);
    s_loc += __shfl_xor(s_loc, 32, 64);
    l_i = l_i * alpha + s_loc;
#pragma unroll
    for (int n = 0; n < 4; ++n)
#pragma unroll
        for (int r = 0; r < 4; ++r) oacc[n][r] *= alpha;
#pragma unroll
    for (int m16 = 0; m16 < 4; ++m16) {
        uint2 u;
        u.x = pk2(p[m16][0], p[m16][1]);
        u.y = pk2(p[m16][2], p[m16][3]);
        const int ch = 2 * m16 + (g >> 1);
        *(uint2*)(Pw + fr * 64 + ((ch ^ (fr & 7)) * 8) + (g & 1) * 4) = u;
    }
    __asm__ __volatile__("" ::: "memory");
    s16x8 pf0 = *(const s16x8*)(Pw + fr * 64 + ((g ^ (fr & 7)) * 8));
    s16x8 pf1 = *(const s16x8*)(Pw + fr * 64 + (((4 + g) ^ (fr & 7)) * 8));
#pragma unroll
    for (int m16 = 0; m16 < 4; ++m16) {
        oacc[m16] = MFMA_BF16(vf[m16][0], pf0, oacc[m16], 0, 0, 0);
        oacc[m16] = MFMA_BF16(vf[m16][1], pf1, oacc[m16], 0, 0, 0);
    }
}

__global__ __launch_bounds__(256, 2) void flash_attn_kernel(
        const unsigned short* __restrict__ Xq, const unsigned short* __restrict__ Xk,
        const unsigned short* __restrict__ Xvt, unsigned short* __restrict__ Oa) {
    __shared__ unsigned short Kls[64 * 64];
    __shared__ unsigned short Vls[64 * 64];
    __shared__ unsigned short Pls[2][4][16 * 64];   // [slab][wave]

    const int t = threadIdx.x;
    const int j = blockIdx.x;                  // 0..15
    const int bh = blockIdx.y;
    const int b = bh >> 4, h = bh & 15;
    const size_t rbase = (size_t)b * 2048;
    const int cbase = h * 64;

    const int w = t >> 6, lane = t & 63, fr = lane & 15, g = lane >> 4, fq = g * 8;
    const int qtH = 31 - j, qtL = j;
    const int qrowH = qtH * 64 + w * 16 + fr;
    const int qrowL = qtL * 64 + w * 16 + fr;

    const unsigned short* qpH = Xq + (rbase + qrowH) * 1024 + cbase;
    s16x8 qfH0 = *(const s16x8*)(qpH + fq);
    s16x8 qfH1 = *(const s16x8*)(qpH + 32 + fq);
    const unsigned short* qpL = Xq + (rbase + qrowL) * 1024 + cbase;
    s16x8 qfL0 = *(const s16x8*)(qpL + fq);
    s16x8 qfL1 = *(const s16x8*)(qpL + 32 + fq);

    const float SCL = 0.125f * 1.44269504089f;  // 1/sqrt(64)*log2(e); exp2 softmax
    float mH = -1e30f, lH = 0.f, mL = -1e30f, lL = 0.f;
    f32x4 oH[4] = {}, oL[4] = {};

    // staging coords: wave w covers tile rows w*16..w*16+15, swizzled image
    const int r0 = w * 16 + (lane >> 3), r1 = r0 + 8;
    const int s8 = lane & 7;
    const int c0 = s8 ^ (r0 & 7), c1 = s8 ^ (r1 & 7);

    for (int kt = 0; kt <= qtH; ++kt) {
        const unsigned short* ks = Xk + (rbase + kt * 64) * 1024 + cbase;
        ald16(Kls + (w * 16) * 64,     ks + (size_t)r0 * 1024 + c0 * 8);
        ald16(Kls + (w * 16 + 8) * 64, ks + (size_t)r1 * 1024 + c1 * 8);
        const unsigned short* vs = Xvt + rbase + kt * 64;
        ald16(Vls + (w * 16) * 64,     vs + (size_t)(cbase + r0) * 4096 + c0 * 8);
        ald16(Vls + (w * 16 + 8) * 64, vs + (size_t)(cbase + r1) * 4096 + c1 * 8);
        __syncthreads();

        const bool doL = (kt <= qtL);

        s16x8 kf[4][2], vf[4][2];
#pragma unroll
        for (int m16 = 0; m16 < 4; ++m16) {
            const int rr = m16 * 16 + fr;
            kf[m16][0] = *(const s16x8*)(Kls + rr * 64 + ((g ^ (fr & 7)) * 8));
            kf[m16][1] = *(const s16x8*)(Kls + rr * 64 + (((4 + g) ^ (fr & 7)) * 8));
            vf[m16][0] = *(const s16x8*)(Vls + rr * 64 + ((g ^ (fr & 7)) * 8));
            vf[m16][1] = *(const s16x8*)(Vls + rr * 64 + (((4 + g) ^ (fr & 7)) * 8));
        }

        f32x4 sH[4], sL[4];
#pragma unroll
        for (int m16 = 0; m16 < 4; ++m16) {
            f32x4 zz = {};
            zz = MFMA_BF16(kf[m16][0], qfH0, zz, 0, 0, 0);
            sH[m16] = MFMA_BF16(kf[m16][1], qfH1, zz, 0, 0, 0);
        }
        if (doL) {
#pragma unroll
            for (int m16 = 0; m16 < 4; ++m16) {
                f32x4 zz = {};
                zz = MFMA_BF16(kf[m16][0], qfL0, zz, 0, 0, 0);
                sL[m16] = MFMA_BF16(kf[m16][1], qfL1, zz, 0, 0, 0);
            }
        }
        slab_tail(sH, kt, qtH, qrowH, mH, lH, oH, &Pls[0][w][0], vf, fr, g, SCL);
        if (doL)
            slab_tail(sL, kt, qtL, qrowL, mL, lL, oL, &Pls[1][w][0], vf, fr, g, SCL);
        __syncthreads();
    }

    const float invH = 1.0f / lH, invL = 1.0f / lL;
#pragma unroll
    for (int m16 = 0; m16 < 4; ++m16) {
        uint2 u;
        u.x = pk2(oH[m16][0] * invH, oH[m16][1] * invH);
        u.y = pk2(oH[m16][2] * invH, oH[m16][3] * invH);
        *(uint2*)(Oa + (rbase + qrowH) * 1024 + cbase + m16 * 16 + g * 4) = u;
        uint2 u2;
        u2.x = pk2(oL[m16][0] * invL, oL[m16][1] * invL);
        u2.y = pk2(oL[m16][2] * invL, oL[m16][3] * invL);
        *(uint2*)(Oa + (rbase + qrowL) * 1024 + cbase + m16 * 16 + g * 4) = u2;
    }
}

// ---------------------------------------------------------------------------
// outproj: out_fp32[4096x1024] = Oa_bf16 @ Wo_bf16^T. 64x128 tile, BK=32,
// full ald16 staging with source-permuted swizzle. grid (8, 64).
// ---------------------------------------------------------------------------
__global__ __launch_bounds__(256) void outproj_kernel(
        const unsigned short* __restrict__ Oa, const unsigned short* __restrict__ Wo,
        float* __restrict__ out) {
    constexpr int Kd = 1024;
    __shared__ unsigned short lsA[64 * 32];
    __shared__ unsigned short lsB[128 * 32];

    const int t = threadIdx.x;
    const int m0 = blockIdx.y * 64, n0 = blockIdx.x * 128;
    const int w = t >> 6, lane = t & 63, fr = lane & 15, g = lane >> 4;
    const int wm = (w >> 1) * 32, wn = (w & 1) * 64;
    const int brow = t >> 2;
    const int cB = (t & 3) ^ ((t >> 3) & 3);
    const int sB = g ^ ((fr >> 1) & 3);

    f32x4 acc[2][4] = {};

    for (int k0 = 0; k0 < Kd; k0 += 32) {
        ald16(lsA + (size_t)w * 512,        Oa + (size_t)(m0 + brow) * Kd + k0 + cB * 8);
        ald16(lsB + (size_t)w * 512,        Wo + (size_t)(n0 + brow) * Kd + k0 + cB * 8);
        ald16(lsB + 2048 + (size_t)w * 512, Wo + (size_t)(n0 + 64 + brow) * Kd + k0 + cB * 8);
        __syncthreads();

        s16x8 af[2], bfv[4];
#pragma unroll
        for (int mi = 0; mi < 2; ++mi)
            af[mi] = *(const s16x8*)(lsA + (wm + mi * 16 + fr) * 32 + sB * 8);
#pragma unroll
        for (int ni = 0; ni < 4; ++ni)
            bfv[ni] = *(const s16x8*)(lsB + (wn + ni * 16 + fr) * 32 + sB * 8);
#pragma unroll
        for (int mi = 0; mi < 2; ++mi)
#pragma unroll
            for (int ni = 0; ni < 4; ++ni)
                acc[mi][ni] = MFMA_BF16(af[mi], bfv[ni], acc[mi][ni], 0, 0, 0);
        __syncthreads();
    }

#pragma unroll
    for (int mi = 0; mi < 2; ++mi)
#pragma unroll
        for (int ni = 0; ni < 4; ++ni)
#pragma unroll
            for (int reg = 0; reg < 4; ++reg)
                out[(size_t)(m0 + wm + mi * 16 + g * 4 + reg) * 1024 +
                    n0 + wn + ni * 16 + fr] = acc[mi][ni][reg];
}

// ---------------------------------------------------------------------------
extern "C" void kernel_launch(void* const* d_in, const int* in_sizes, int n_in,
                              void* d_out, int out_size, void* d_ws, size_t ws_size,
                              hipStream_t stream) {
    const float* q  = (const float*)d_in[0];
    const float* k  = (const float*)d_in[1];
    const float* v  = (const float*)d_in[2];
    const float* wq = (const float*)d_in[3];
    const float* wk = (const float*)d_in[4];
    const float* wv = (const float*)d_in[5];
    const float* wo = (const float*)d_in[6];
    float* out = (float*)d_out;

    // workspace: Wb 8MB | Xq 8MB | Xk 8MB | Xvt 8MB | Oa 8MB  (40MB total)
    unsigned short* Wb  = (unsigned short*)d_ws;
    unsigned short* Xq  = Wb  + 4 * 1048576;
    unsigned short* Xk  = Xq  + 4194304;
    unsigned short* Xvt = Xk  + 4194304;
    unsigned short* Oa  = Xvt + 4194304;

    wconvert_kernel<<<2048, 256, 0, stream>>>(wq, wk, wv, wo, Wb);
    proj3_kernel<<<dim3(8, 32, 3), 256, 0, stream>>>(q, k, v, Wb, Xq, Xk, Xvt);
    flash_attn_kernel<<<dim3(16, 32), 256, 0, stream>>>(Xq, Xk, Xvt, Oa);
    outproj_kernel<<<dim3(8, 64), 256, 0, stream>>>(Oa, Wb + 3 * 1048576, out);
}

// Round 5
// 213.940 us; speedup vs baseline: 1.3024x; 1.1430x over previous
//
#include <hip/hip_runtime.h>
#include <stdint.h>

// MHA: B=2, S=2048, DIM=1024, H=16, HD=64, causal. fp32 I/O, bf16 MFMA internal.
// Pipeline: convert_all (q,k,v,weights -> bf16) -> proj3b (all-ald16 GEMM) ->
//           flash (transposed-S, balanced q-tile pairs) -> outproj.
// All grids XCD-swizzled: shared-A readers differ by multiples of 8 in linear
// block id -> same XCD -> L2-shared (round-robin block->XCD dispatch).

typedef short s16x8 __attribute__((ext_vector_type(8)));
typedef float f32x4 __attribute__((ext_vector_type(4)));

#define MFMA_BF16 __builtin_amdgcn_mfma_f32_16x16x32_bf16

static __device__ __forceinline__ unsigned short f2bf(float f) {
    union { float f; unsigned u; } x{f};
    unsigned r = x.u + 0x7fff + ((x.u >> 16) & 1);   // RNE
    return (unsigned short)(r >> 16);
}
static __device__ __forceinline__ unsigned pk2(float a, float b) {
    return (unsigned)f2bf(a) | ((unsigned)f2bf(b) << 16);
}

// async 16B global->LDS: dest is wave-uniform base, lane i lands at base + i*16B.
static __device__ __forceinline__ void ald16(unsigned short* lds, const unsigned short* g) {
    __builtin_amdgcn_global_load_lds(
        (const __attribute__((address_space(1))) unsigned int*)g,
        (__attribute__((address_space(3))) unsigned int*)lds, 16, 0, 0);
}

// ---------------------------------------------------------------------------
// convert_all: q,k,v (4M elems each) + wq,wk,wv,wo (1M each) fp32 -> bf16,
// written contiguously at ws base: [Qb|Kb|Vb|Wq|Wk|Wv|Wo]. grid 8192x256.
// ---------------------------------------------------------------------------
__global__ __launch_bounds__(256) void convert_all_kernel(
        const float* __restrict__ q, const float* __restrict__ k,
        const float* __restrict__ v,
        const float* __restrict__ wq, const float* __restrict__ wk,
        const float* __restrict__ wv, const float* __restrict__ wo,
        unsigned short* __restrict__ dst) {
    const size_t idx = ((size_t)blockIdx.x * 256 + threadIdx.x) * 8;
    const int region = (int)(idx >> 22);                 // 4M-elem regions
    const float* src;
    size_t off;
    if (region == 0)      { src = q; off = idx; }
    else if (region == 1) { src = k; off = idx & 4194303; }
    else if (region == 2) { src = v; off = idx & 4194303; }
    else {
        const int wsel = (int)((idx >> 20) & 3);         // 1M-elem sub-regions
        src = wsel == 0 ? wq : wsel == 1 ? wk : wsel == 2 ? wv : wo;
        off = idx & 1048575;
    }
    const float4* p = (const float4*)(src + off);
    float4 a = p[0], b = p[1];
    uint4 u;
    u.x = pk2(a.x, a.y); u.y = pk2(a.z, a.w);
    u.z = pk2(b.x, b.y); u.w = pk2(b.z, b.w);
    *(uint4*)(dst + idx) = u;
}

// wconvert (fallback path): weights only -> Wb[4M]
__global__ __launch_bounds__(256) void wconvert_kernel(
        const float* __restrict__ wq, const float* __restrict__ wk,
        const float* __restrict__ wv, const float* __restrict__ wo,
        unsigned short* __restrict__ Wb) {
    const size_t idx = ((size_t)blockIdx.x * 256 + threadIdx.x) * 8;
    const int region = (int)(idx >> 20);
    const size_t off = idx & 1048575;
    const float* src = region == 0 ? wq : region == 1 ? wk : region == 2 ? wv : wo;
    const float4* p = (const float4*)(src + off);
    float4 a = p[0], b = p[1];
    uint4 u;
    u.x = pk2(a.x, a.y); u.y = pk2(a.z, a.w);
    u.z = pk2(b.x, b.y); u.w = pk2(b.z, b.w);
    *(uint4*)(Wb + idx) = u;
}

// ---------------------------------------------------------------------------
// proj3b: C[4096x1024] = A_bf16 @ W_bf16^T. 128x128 tile, BK=32, full ald16
// staging (m97 structure). grid (32,8,3): x->m (XCD-local A), y->n.
// z==2: transpose epilogue via LDS -> coalesced Xvt[dim][token].
// ---------------------------------------------------------------------------
__global__ __launch_bounds__(256) void proj3b_kernel(
        const unsigned short* __restrict__ Qb, const unsigned short* __restrict__ Kb,
        const unsigned short* __restrict__ Vb, const unsigned short* __restrict__ Wb,
        unsigned short* __restrict__ Xq, unsigned short* __restrict__ Xk,
        unsigned short* __restrict__ Xvt) {
    constexpr int Kd = 1024;
    __shared__ union {
        struct { unsigned short A[128 * 32]; unsigned short B[128 * 32]; } s;
        unsigned short T[4 * 64 * 68];          // per-wave transpose tile (z==2)
    } sm;

    const int z = blockIdx.z;
    const unsigned short* A  = z == 0 ? Qb : z == 1 ? Kb : Vb;
    const unsigned short* Bw = Wb + (size_t)z * 1048576;

    const int t = threadIdx.x;
    const int m0 = blockIdx.x * 128, n0 = blockIdx.y * 128;
    const int w = t >> 6, lane = t & 63, fr = lane & 15, g = lane >> 4;
    const int wm = (w >> 1) * 64, wn = (w & 1) * 64;
    const int brow = t >> 2;                             // staging row 0..63
    const int cB = (t & 3) ^ ((t >> 3) & 3);             // permuted source chunk
    const int sB = g ^ ((fr >> 1) & 3);                  // frag-read slot

    f32x4 acc[4][4] = {};

    for (int k0 = 0; k0 < Kd; k0 += 32) {
        ald16(sm.s.A + (size_t)w * 512,        A  + (size_t)(m0 + brow) * Kd + k0 + cB * 8);
        ald16(sm.s.A + 2048 + (size_t)w * 512, A  + (size_t)(m0 + 64 + brow) * Kd + k0 + cB * 8);
        ald16(sm.s.B + (size_t)w * 512,        Bw + (size_t)(n0 + brow) * Kd + k0 + cB * 8);
        ald16(sm.s.B + 2048 + (size_t)w * 512, Bw + (size_t)(n0 + 64 + brow) * Kd + k0 + cB * 8);
        __syncthreads();

        s16x8 af[4], bfv[4];
#pragma unroll
        for (int mi = 0; mi < 4; ++mi)
            af[mi] = *(const s16x8*)(sm.s.A + (wm + mi * 16 + fr) * 32 + sB * 8);
#pragma unroll
        for (int ni = 0; ni < 4; ++ni)
            bfv[ni] = *(const s16x8*)(sm.s.B + (wn + ni * 16 + fr) * 32 + sB * 8);
#pragma unroll
        for (int mi = 0; mi < 4; ++mi)
#pragma unroll
            for (int ni = 0; ni < 4; ++ni)
                acc[mi][ni] = MFMA_BF16(af[mi], bfv[ni], acc[mi][ni], 0, 0, 0);
        __syncthreads();
    }

    if (z != 2) {
        unsigned short* C = z ? Xk : Xq;
#pragma unroll
        for (int mi = 0; mi < 4; ++mi)
#pragma unroll
            for (int ni = 0; ni < 4; ++ni)
#pragma unroll
                for (int reg = 0; reg < 4; ++reg)
                    C[(size_t)(m0 + wm + mi * 16 + g * 4 + reg) * 1024 +
                      n0 + wn + ni * 16 + fr] = f2bf(acc[mi][ni][reg]);
    } else {
        unsigned short* T = sm.T + w * (64 * 68);
#pragma unroll
        for (int mi = 0; mi < 4; ++mi)
#pragma unroll
            for (int ni = 0; ni < 4; ++ni) {
                uint2 u;
                u.x = pk2(acc[mi][ni][0], acc[mi][ni][1]);
                u.y = pk2(acc[mi][ni][2], acc[mi][ni][3]);
                *(uint2*)(T + (ni * 16 + fr) * 68 + mi * 16 + g * 4) = u;
            }
        __asm__ __volatile__("" ::: "memory");
#pragma unroll
        for (int pass = 0; pass < 8; ++pass) {
            const int row = pass * 8 + (lane >> 3);
            const int chk = lane & 7;
            uint4 d = *(const uint4*)(T + row * 68 + chk * 8);
            *(uint4*)(Xvt + (size_t)(n0 + wn + row) * 4096 + m0 + wm + chk * 8) = d;
        }
    }
}

// ---------------------------------------------------------------------------
// proj3 (fallback, fp32 A): as r4 but grid (32,8,3) x->m, y->n.
// ---------------------------------------------------------------------------
__global__ __launch_bounds__(256) void proj3_kernel(
        const float* __restrict__ q, const float* __restrict__ k, const float* __restrict__ v,
        const unsigned short* __restrict__ Wb,
        unsigned short* __restrict__ Xq, unsigned short* __restrict__ Xk,
        unsigned short* __restrict__ Xvt) {
    constexpr int Kd = 1024;
    __shared__ unsigned short lsA[128 * 40];
    __shared__ unsigned short lsB[128 * 32];
    __shared__ unsigned short Tls[4 * 64 * 68];

    const int z = blockIdx.z;
    const float* A = z == 0 ? q : z == 1 ? k : v;
    const unsigned short* Bw = Wb + (size_t)z * 1048576;

    const int t = threadIdx.x;
    const int m0 = blockIdx.x * 128, n0 = blockIdx.y * 128;
    const int w = t >> 6, lane = t & 63, fr = lane & 15, g = lane >> 4, fq = g * 8;
    const int wm = (w >> 1) * 64, wn = (w & 1) * 64;
    const int ar = t >> 1, ac = (t & 1) * 16;
    const int brow = t >> 2;
    const int cB = (t & 3) ^ ((t >> 3) & 3);
    const int sB = g ^ ((fr >> 1) & 3);

    f32x4 acc[4][4] = {};

    for (int k0 = 0; k0 < Kd; k0 += 32) {
        ald16(lsB + (size_t)w * 512,        Bw + (size_t)(n0 + brow) * Kd + k0 + cB * 8);
        ald16(lsB + 2048 + (size_t)w * 512, Bw + (size_t)(n0 + 64 + brow) * Kd + k0 + cB * 8);
        {
            const float4* pa = (const float4*)(A + (size_t)(m0 + ar) * Kd + k0 + ac);
            float4 a0 = pa[0], a1 = pa[1], a2 = pa[2], a3 = pa[3];
            uint4 u0, u1;
            u0.x = pk2(a0.x, a0.y); u0.y = pk2(a0.z, a0.w);
            u0.z = pk2(a1.x, a1.y); u0.w = pk2(a1.z, a1.w);
            u1.x = pk2(a2.x, a2.y); u1.y = pk2(a2.z, a2.w);
            u1.z = pk2(a3.x, a3.y); u1.w = pk2(a3.z, a3.w);
            *(uint4*)(lsA + ar * 40 + ac)     = u0;
            *(uint4*)(lsA + ar * 40 + ac + 8) = u1;
        }
        __syncthreads();

        s16x8 af[4], bfv[4];
#pragma unroll
        for (int mi = 0; mi < 4; ++mi)
            af[mi] = *(const s16x8*)(lsA + (wm + mi * 16 + fr) * 40 + fq);
#pragma unroll
        for (int ni = 0; ni < 4; ++ni)
            bfv[ni] = *(const s16x8*)(lsB + (wn + ni * 16 + fr) * 32 + sB * 8);
#pragma unroll
        for (int mi = 0; mi < 4; ++mi)
#pragma unroll
            for (int ni = 0; ni < 4; ++ni)
                acc[mi][ni] = MFMA_BF16(af[mi], bfv[ni], acc[mi][ni], 0, 0, 0);
        __syncthreads();
    }

    if (z != 2) {
        unsigned short* C = z ? Xk : Xq;
#pragma unroll
        for (int mi = 0; mi < 4; ++mi)
#pragma unroll
            for (int ni = 0; ni < 4; ++ni)
#pragma unroll
                for (int reg = 0; reg < 4; ++reg)
                    C[(size_t)(m0 + wm + mi * 16 + g * 4 + reg) * 1024 +
                      n0 + wn + ni * 16 + fr] = f2bf(acc[mi][ni][reg]);
    } else {
        unsigned short* T = Tls + w * (64 * 68);
#pragma unroll
        for (int mi = 0; mi < 4; ++mi)
#pragma unroll
            for (int ni = 0; ni < 4; ++ni) {
                uint2 u;
                u.x = pk2(acc[mi][ni][0], acc[mi][ni][1]);
                u.y = pk2(acc[mi][ni][2], acc[mi][ni][3]);
                *(uint2*)(T + (ni * 16 + fr) * 68 + mi * 16 + g * 4) = u;
            }
        __asm__ __volatile__("" ::: "memory");
#pragma unroll
        for (int pass = 0; pass < 8; ++pass) {
            const int row = pass * 8 + (lane >> 3);
            const int chk = lane & 7;
            uint4 d = *(const uint4*)(T + row * 68 + chk * 8);
            *(uint4*)(Xvt + (size_t)(n0 + wn + row) * 4096 + m0 + wm + chk * 8) = d;
        }
    }
}

// ---------------------------------------------------------------------------
// flash attention, transposed-S, balanced q-tile pairs.
// grid (32 bh, 16 j): x->bh so the 16 j-blocks sharing K/V land on one XCD.
// ---------------------------------------------------------------------------
static __device__ __forceinline__ void slab_tail(
        const f32x4 sf[4], int kt, int qt, int qrow,
        float& m_i, float& l_i, f32x4* oacc, unsigned short* Pw,
        const s16x8 vf[4][2], int fr, int g, float SCL) {
    float p[4][4];
    float mloc = -1e30f;
    const bool diag = (kt == qt);
#pragma unroll
    for (int m16 = 0; m16 < 4; ++m16)
#pragma unroll
        for (int r = 0; r < 4; ++r) {
            const int keyg = kt * 64 + m16 * 16 + g * 4 + r;
            float x = sf[m16][r] * SCL;
            if (diag) x = (keyg <= qrow) ? x : -1e30f;
            p[m16][r] = x;
            mloc = fmaxf(mloc, x);
        }
    mloc = fmaxf(mloc, __shfl_xor(mloc, 16, 64));
    mloc = fmaxf(mloc, __shfl_xor(mloc, 32, 64));
    const float mn = fmaxf(m_i, mloc);
    const float alpha = exp2f(m_i - mn);
    m_i = mn;
    float s_loc = 0.f;
#pragma unroll
    for (int m16 = 0; m16 < 4; ++m16)
#pragma unroll
        for (int r = 0; r < 4; ++r) {
            const float e = exp2f(p[m16][r] - mn);
            p[m16][r] = e;
            s_loc += e;
        }
    s_loc += __shfl_xor(s_loc, 16, 64);
    s_loc += __shfl_xor(s_loc, 32, 64);
    l_i = l_i * alpha + s_loc;
#pragma unroll
    for (int n = 0; n < 4; ++n)
#pragma unroll
        for (int r = 0; r < 4; ++r) oacc[n][r] *= alpha;
#pragma unroll
    for (int m16 = 0; m16 < 4; ++m16) {
        uint2 u;
        u.x = pk2(p[m16][0], p[m16][1]);
        u.y = pk2(p[m16][2], p[m16][3]);
        const int ch = 2 * m16 + (g >> 1);
        *(uint2*)(Pw + fr * 64 + ((ch ^ (fr & 7)) * 8) + (g & 1) * 4) = u;
    }
    __asm__ __volatile__("" ::: "memory");
    s16x8 pf0 = *(const s16x8*)(Pw + fr * 64 + ((g ^ (fr & 7)) * 8));
    s16x8 pf1 = *(const s16x8*)(Pw + fr * 64 + (((4 + g) ^ (fr & 7)) * 8));
#pragma unroll
    for (int m16 = 0; m16 < 4; ++m16) {
        oacc[m16] = MFMA_BF16(vf[m16][0], pf0, oacc[m16], 0, 0, 0);
        oacc[m16] = MFMA_BF16(vf[m16][1], pf1, oacc[m16], 0, 0, 0);
    }
}

__global__ __launch_bounds__(256, 2) void flash_attn_kernel(
        const unsigned short* __restrict__ Xq, const unsigned short* __restrict__ Xk,
        const unsigned short* __restrict__ Xvt, unsigned short* __restrict__ Oa) {
    __shared__ unsigned short Kls[64 * 64];
    __shared__ unsigned short Vls[64 * 64];
    __shared__ unsigned short Pls[2][4][16 * 64];   // [slab][wave]

    const int t = threadIdx.x;
    const int bh = blockIdx.x;                 // 0..31 (fast dim -> XCD-local K/V)
    const int j = blockIdx.y;                  // 0..15
    const int b = bh >> 4, h = bh & 15;
    const size_t rbase = (size_t)b * 2048;
    const int cbase = h * 64;

    const int w = t >> 6, lane = t & 63, fr = lane & 15, g = lane >> 4, fq = g * 8;
    const int qtH = 31 - j, qtL = j;
    const int qrowH = qtH * 64 + w * 16 + fr;
    const int qrowL = qtL * 64 + w * 16 + fr;

    const unsigned short* qpH = Xq + (rbase + qrowH) * 1024 + cbase;
    s16x8 qfH0 = *(const s16x8*)(qpH + fq);
    s16x8 qfH1 = *(const s16x8*)(qpH + 32 + fq);
    const unsigned short* qpL = Xq + (rbase + qrowL) * 1024 + cbase;
    s16x8 qfL0 = *(const s16x8*)(qpL + fq);
    s16x8 qfL1 = *(const s16x8*)(qpL + 32 + fq);

    const float SCL = 0.125f * 1.44269504089f;  // 1/sqrt(64)*log2(e); exp2 softmax
    float mH = -1e30f, lH = 0.f, mL = -1e30f, lL = 0.f;
    f32x4 oH[4] = {}, oL[4] = {};

    const int r0 = w * 16 + (lane >> 3), r1 = r0 + 8;
    const int s8 = lane & 7;
    const int c0 = s8 ^ (r0 & 7), c1 = s8 ^ (r1 & 7);

    for (int kt = 0; kt <= qtH; ++kt) {
        const unsigned short* ks = Xk + (rbase + kt * 64) * 1024 + cbase;
        ald16(Kls + (w * 16) * 64,     ks + (size_t)r0 * 1024 + c0 * 8);
        ald16(Kls + (w * 16 + 8) * 64, ks + (size_t)r1 * 1024 + c1 * 8);
        const unsigned short* vs = Xvt + rbase + kt * 64;
        ald16(Vls + (w * 16) * 64,     vs + (size_t)(cbase + r0) * 4096 + c0 * 8);
        ald16(Vls + (w * 16 + 8) * 64, vs + (size_t)(cbase + r1) * 4096 + c1 * 8);
        __syncthreads();

        const bool doL = (kt <= qtL);

        s16x8 kf[4][2], vf[4][2];
#pragma unroll
        for (int m16 = 0; m16 < 4; ++m16) {
            const int rr = m16 * 16 + fr;
            kf[m16][0] = *(const s16x8*)(Kls + rr * 64 + ((g ^ (fr & 7)) * 8));
            kf[m16][1] = *(const s16x8*)(Kls + rr * 64 + (((4 + g) ^ (fr & 7)) * 8));
            vf[m16][0] = *(const s16x8*)(Vls + rr * 64 + ((g ^ (fr & 7)) * 8));
            vf[m16][1] = *(const s16x8*)(Vls + rr * 64 + (((4 + g) ^ (fr & 7)) * 8));
        }

        f32x4 sH[4], sL[4];
#pragma unroll
        for (int m16 = 0; m16 < 4; ++m16) {
            f32x4 zz = {};
            zz = MFMA_BF16(kf[m16][0], qfH0, zz, 0, 0, 0);
            sH[m16] = MFMA_BF16(kf[m16][1], qfH1, zz, 0, 0, 0);
        }
        if (doL) {
#pragma unroll
            for (int m16 = 0; m16 < 4; ++m16) {
                f32x4 zz = {};
                zz = MFMA_BF16(kf[m16][0], qfL0, zz, 0, 0, 0);
                sL[m16] = MFMA_BF16(kf[m16][1], qfL1, zz, 0, 0, 0);
            }
        }
        slab_tail(sH, kt, qtH, qrowH, mH, lH, oH, &Pls[0][w][0], vf, fr, g, SCL);
        if (doL)
            slab_tail(sL, kt, qtL, qrowL, mL, lL, oL, &Pls[1][w][0], vf, fr, g, SCL);
        __syncthreads();
    }

    const float invH = 1.0f / lH, invL = 1.0f / lL;
#pragma unroll
    for (int m16 = 0; m16 < 4; ++m16) {
        uint2 u;
        u.x = pk2(oH[m16][0] * invH, oH[m16][1] * invH);
        u.y = pk2(oH[m16][2] * invH, oH[m16][3] * invH);
        *(uint2*)(Oa + (rbase + qrowH) * 1024 + cbase + m16 * 16 + g * 4) = u;
        uint2 u2;
        u2.x = pk2(oL[m16][0] * invL, oL[m16][1] * invL);
        u2.y = pk2(oL[m16][2] * invL, oL[m16][3] * invL);
        *(uint2*)(Oa + (rbase + qrowL) * 1024 + cbase + m16 * 16 + g * 4) = u2;
    }
}

// ---------------------------------------------------------------------------
// outproj: out_fp32[4096x1024] = Oa_bf16 @ Wo_bf16^T. 64x128 tile, BK=32,
// full ald16 staging. grid (64, 8): x->m (XCD-local A), y->n.
// ---------------------------------------------------------------------------
__global__ __launch_bounds__(256) void outproj_kernel(
        const unsigned short* __restrict__ Oa, const unsigned short* __restrict__ Wo,
        float* __restrict__ out) {
    constexpr int Kd = 1024;
    __shared__ unsigned short lsA[64 * 32];
    __shared__ unsigned short lsB[128 * 32];

    const int t = threadIdx.x;
    const int m0 = blockIdx.x * 64, n0 = blockIdx.y * 128;
    const int w = t >> 6, lane = t & 63, fr = lane & 15, g = lane >> 4;
    const int wm = (w >> 1) * 32, wn = (w & 1) * 64;
    const int brow = t >> 2;
    const int cB = (t & 3) ^ ((t >> 3) & 3);
    const int sB = g ^ ((fr >> 1) & 3);

    f32x4 acc[2][4] = {};

    for (int k0 = 0; k0 < Kd; k0 += 32) {
        ald16(lsA + (size_t)w * 512,        Oa + (size_t)(m0 + brow) * Kd + k0 + cB * 8);
        ald16(lsB + (size_t)w * 512,        Wo + (size_t)(n0 + brow) * Kd + k0 + cB * 8);
        ald16(lsB + 2048 + (size_t)w * 512, Wo + (size_t)(n0 + 64 + brow) * Kd + k0 + cB * 8);
        __syncthreads();

        s16x8 af[2], bfv[4];
#pragma unroll
        for (int mi = 0; mi < 2; ++mi)
            af[mi] = *(const s16x8*)(lsA + (wm + mi * 16 + fr) * 32 + sB * 8);
#pragma unroll
        for (int ni = 0; ni < 4; ++ni)
            bfv[ni] = *(const s16x8*)(lsB + (wn + ni * 16 + fr) * 32 + sB * 8);
#pragma unroll
        for (int mi = 0; mi < 2; ++mi)
#pragma unroll
            for (int ni = 0; ni < 4; ++ni)
                acc[mi][ni] = MFMA_BF16(af[mi], bfv[ni], acc[mi][ni], 0, 0, 0);
        __syncthreads();
    }

#pragma unroll
    for (int mi = 0; mi < 2; ++mi)
#pragma unroll
        for (int ni = 0; ni < 4; ++ni)
#pragma unroll
            for (int reg = 0; reg < 4; ++reg)
                out[(size_t)(m0 + wm + mi * 16 + g * 4 + reg) * 1024 +
                    n0 + wn + ni * 16 + fr] = acc[mi][ni][reg];
}

// ---------------------------------------------------------------------------
extern "C" void kernel_launch(void* const* d_in, const int* in_sizes, int n_in,
                              void* d_out, int out_size, void* d_ws, size_t ws_size,
                              hipStream_t stream) {
    const float* q  = (const float*)d_in[0];
    const float* k  = (const float*)d_in[1];
    const float* v  = (const float*)d_in[2];
    const float* wq = (const float*)d_in[3];
    const float* wk = (const float*)d_in[4];
    const float* wv = (const float*)d_in[5];
    const float* wo = (const float*)d_in[6];
    float* out = (float*)d_out;

    if (ws_size >= (size_t)64 * 1024 * 1024) {
        // layout (elems): Qb 0 | Kb 4M | Vb 8M | Wb 12M (4x1M) | Xq 16M | Xk 20M
        //                 | Xvt 24M | Oa 28M   (= 64 MB)
        unsigned short* base = (unsigned short*)d_ws;
        unsigned short* Qb  = base;
        unsigned short* Kb  = base + 4194304;
        unsigned short* Vb  = base + 8388608;
        unsigned short* Wb  = base + 12582912;
        unsigned short* Xq  = base + 16777216;
        unsigned short* Xk  = base + 20971520;
        unsigned short* Xvt = base + 25165824;
        unsigned short* Oa  = base + 29360128;

        convert_all_kernel<<<8192, 256, 0, stream>>>(q, k, v, wq, wk, wv, wo, base);
        proj3b_kernel<<<dim3(32, 8, 3), 256, 0, stream>>>(Qb, Kb, Vb, Wb, Xq, Xk, Xvt);
        flash_attn_kernel<<<dim3(32, 16), 256, 0, stream>>>(Xq, Xk, Xvt, Oa);
        outproj_kernel<<<dim3(64, 8), 256, 0, stream>>>(Oa, Wb + 3145728, out);
    } else {
        // fallback 40 MB layout: Wb | Xq | Xk | Xvt | Oa
        unsigned short* Wb  = (unsigned short*)d_ws;
        unsigned short* Xq  = Wb  + 4194304;
        unsigned short* Xk  = Xq  + 4194304;
        unsigned short* Xvt = Xk  + 4194304;
        unsigned short* Oa  = Xvt + 4194304;

        wconvert_kernel<<<2048, 256, 0, stream>>>(wq, wk, wv, wo, Wb);
        proj3_kernel<<<dim3(32, 8, 3), 256, 0, stream>>>(q, k, v, Wb, Xq, Xk, Xvt);
        flash_attn_kernel<<<dim3(32, 16), 256, 0, stream>>>(Xq, Xk, Xvt, Oa);
        outproj_kernel<<<dim3(64, 8), 256, 0, stream>>>(Oa, Wb + 3145728, out);
    }
}